// Round 1
// baseline (2052.104 us; speedup 1.0000x reference)
//
#include <hip/hip_runtime.h>
#include <hip/hip_bf16.h>

#define N_NODES 100000
#define F_IN 1433
#define H1F 32
#define H2F 16
#define NBLK_SCAN 98   // ceil(100000/1024)

typedef __bf16 bf16x8 __attribute__((ext_vector_type(8)));
typedef float f32x4 __attribute__((ext_vector_type(4)));

// ---- workspace layout (float offsets) ----
// zeroed region (one memset): cnt, lse_acc
#define O_H1ACC 0          // 3,200,000 f  (N*32) -> h1 (written fully by k_agg1)
#define O_H2ACC 3200000    // 1,600,000 f  (N*16) -> h2 (written fully by k_agg2)
#define O_CNT   4800000    // 100,000 int  (degree counts)       [zeroed]
#define O_LSE   4900000    // 100,000 f    (sum-exp accum)       [zeroed]
#define O_H1PRE 5000000    // 3,200,000 f  (x@W1)
#define O_H2PRE 8200000    // 1,600,000 f  (h1@W2)
#define O_DISQ  9800000    // 100,000 f    (deg^-1/2)
#define O_WLT   9900000    // 24,000 f     (Wl transposed [1433][16])
#define O_W1F   9924000    // 23,040 f     (W1 packed bf16 B-fragments)

// ---------------- degree / normalization ----------------
__global__ void k_deg(const int* __restrict__ dst, int E, int* __restrict__ cnt) {
    int t = blockIdx.x * 256 + threadIdx.x;
    if (t < E) atomicAdd(&cnt[dst[t]], 1);
}

__global__ void k_disq(const int* __restrict__ cnt, float* __restrict__ disq) {
    int t = blockIdx.x * 256 + threadIdx.x;
    if (t < N_NODES) disq[t] = rsqrtf((float)(cnt[t] + 1));  // +1 self-loop
}

// ---------------- CSR build: 3-kernel coalesced exclusive scan + fill ----------------
// scan phase A: per-1024-element block sums
__global__ __launch_bounds__(256) void k_scansum(const int* __restrict__ cnt,
                                                 int* __restrict__ bsum) {
    __shared__ int lds[256];
    int t = threadIdx.x, b = blockIdx.x;
    int i = b * 1024 + t * 4;
    int c0 = 0, c1 = 0, c2 = 0, c3 = 0;
    if (i + 3 < N_NODES) {
        int4 v = *(const int4*)(cnt + i);
        c0 = v.x; c1 = v.y; c2 = v.z; c3 = v.w;
    } else {
        if (i + 0 < N_NODES) c0 = cnt[i + 0];
        if (i + 1 < N_NODES) c1 = cnt[i + 1];
        if (i + 2 < N_NODES) c2 = cnt[i + 2];
        if (i + 3 < N_NODES) c3 = cnt[i + 3];
    }
    lds[t] = c0 + c1 + c2 + c3;
    __syncthreads();
    for (int off = 128; off > 0; off >>= 1) {
        if (t < off) lds[t] += lds[t + off];
        __syncthreads();
    }
    if (t == 0) bsum[b] = lds[0];
}

// scan phase B: exclusive scan of the 98 block sums (single block)
__global__ __launch_bounds__(128) void k_scanbase(const int* __restrict__ bsum,
                                                  int* __restrict__ bbase,
                                                  int* __restrict__ rowptr) {
    __shared__ int lds[128];
    int t = threadIdx.x;
    lds[t] = (t < NBLK_SCAN) ? bsum[t] : 0;
    __syncthreads();
    for (int off = 1; off < 128; off <<= 1) {
        int u = (t >= off) ? lds[t - off] : 0;
        __syncthreads();
        lds[t] += u;
        __syncthreads();
    }
    bbase[t] = (t == 0) ? 0 : lds[t - 1];
    if (t == NBLK_SCAN - 1) rowptr[N_NODES] = lds[t];  // total in-degree = E
}

// scan phase C: per-element exclusive prefix -> rowptr, fill
__global__ __launch_bounds__(256) void k_scanwrite(const int* __restrict__ cnt,
                                                   const int* __restrict__ bbase,
                                                   int* __restrict__ rowptr,
                                                   int* __restrict__ fill) {
    __shared__ int lds[256];
    int t = threadIdx.x, b = blockIdx.x;
    int i = b * 1024 + t * 4;
    int c0 = 0, c1 = 0, c2 = 0, c3 = 0;
    if (i + 3 < N_NODES) {
        int4 v = *(const int4*)(cnt + i);
        c0 = v.x; c1 = v.y; c2 = v.z; c3 = v.w;
    } else {
        if (i + 0 < N_NODES) c0 = cnt[i + 0];
        if (i + 1 < N_NODES) c1 = cnt[i + 1];
        if (i + 2 < N_NODES) c2 = cnt[i + 2];
        if (i + 3 < N_NODES) c3 = cnt[i + 3];
    }
    int s = c0 + c1 + c2 + c3;
    lds[t] = s;
    __syncthreads();
    for (int off = 1; off < 256; off <<= 1) {
        int u = (t >= off) ? lds[t - off] : 0;
        __syncthreads();
        lds[t] += u;
        __syncthreads();
    }
    int p = bbase[b] + lds[t] - s;  // exclusive prefix for this thread's 4 elems
    if (i + 0 < N_NODES) { rowptr[i + 0] = p; fill[i + 0] = p; p += c0; }
    if (i + 1 < N_NODES) { rowptr[i + 1] = p; fill[i + 1] = p; p += c1; }
    if (i + 2 < N_NODES) { rowptr[i + 2] = p; fill[i + 2] = p; p += c2; }
    if (i + 3 < N_NODES) { rowptr[i + 3] = p; fill[i + 3] = p; p += c3; }
}

// bucket edges by dst: csr[slot] = src  (3.2M int atomics, once, reused by both layers)
__global__ void k_fill(const int* __restrict__ src, const int* __restrict__ dst, int E,
                       int* __restrict__ fill, int* __restrict__ csr) {
    int t = blockIdx.x * 256 + threadIdx.x;
    if (t < E) {
        int slot = atomicAdd(&fill[dst[t]], 1);
        csr[slot] = src[t];
    }
}

// ---------------- W1 -> bf16 B-fragment pack ----------------
// layout: [ks 0..44][ntile 0..1][lane 0..63][j 0..7]; B[k][n]: n=lane&15, k=ks*32+(lane>>4)*8+j
__global__ void k_w1f(const float* __restrict__ W1, __bf16* __restrict__ w1f) {
    int t = blockIdx.x * 256 + threadIdx.x;
    if (t >= 45 * 1024) return;
    int j = t & 7, lane = (t >> 3) & 63, nt = (t >> 9) & 1, ks = t >> 10;
    int k = ks * 32 + (lane >> 4) * 8 + j;
    int f = nt * 16 + (lane & 15);
    float v = (k < F_IN) ? W1[k * H1F + f] : 0.f;  // zero-pad K tail: A garbage * B 0 = 0
    w1f[t] = (__bf16)v;
}

// ---------------- Wl transpose: wlt[j*16+k] = Wl[k*F_IN+j] ----------------
__global__ void k_wlt(const float* __restrict__ Wl, float* __restrict__ wlt) {
    int t = blockIdx.x * 256 + threadIdx.x;
    if (t < F_IN * H2F) {
        int j = t >> 4, k = t & 15;
        wlt[t] = Wl[k * F_IN + j];
    }
}

// ---------------- GEMM1: h1pre = x @ W1  (bf16 MFMA, A direct from global) ----------------
__global__ __launch_bounds__(256) void k_gemm1(const float* __restrict__ x,
                                               const __bf16* __restrict__ w1f,
                                               float* __restrict__ h1pre) {
    const int lane = threadIdx.x & 63;
    const int wv   = threadIdx.x >> 6;
    const int l16  = lane & 15, quad = lane >> 4;
    const int rowb = blockIdx.x * 128 + wv * 32;     // wave owns 32 rows (2 m-tiles)
    const long r0 = min(rowb + l16, N_NODES - 1);
    const long r1 = min(rowb + 16 + l16, N_NODES - 1);
    const float* xr0 = x + r0 * F_IN;
    const float* xr1 = x + r1 * F_IN;
    f32x4 acc00 = {0,0,0,0}, acc01 = {0,0,0,0}, acc10 = {0,0,0,0}, acc11 = {0,0,0,0};
    const bf16x8* bfp = (const bf16x8*)w1f;

    for (int ks = 0; ks < 45; ks++) {
        int kb = ks * 32 + quad * 8;
        bf16x8 a0, a1;
#pragma unroll
        for (int j = 0; j < 8; j++) {
            int k = kb + j; k = k > (F_IN - 1) ? (F_IN - 1) : k;  // clamped: B=0 past 1432
            a0[j] = (__bf16)xr0[k];
            a1[j] = (__bf16)xr1[k];
        }
        bf16x8 b0 = bfp[(ks * 2 + 0) * 64 + lane];
        bf16x8 b1 = bfp[(ks * 2 + 1) * 64 + lane];
        acc00 = __builtin_amdgcn_mfma_f32_16x16x32_bf16(a0, b0, acc00, 0, 0, 0);
        acc01 = __builtin_amdgcn_mfma_f32_16x16x32_bf16(a0, b1, acc01, 0, 0, 0);
        acc10 = __builtin_amdgcn_mfma_f32_16x16x32_bf16(a1, b0, acc10, 0, 0, 0);
        acc11 = __builtin_amdgcn_mfma_f32_16x16x32_bf16(a1, b1, acc11, 0, 0, 0);
    }
    // C/D: col = lane&15 (=f), row = quad*4 + reg (node offset in tile)
#pragma unroll
    for (int reg = 0; reg < 4; reg++) {
        int m0 = rowb + quad * 4 + reg;
        int m1 = m0 + 16;
        if (m0 < N_NODES) {
            h1pre[(long)m0 * 32 + l16]      = acc00[reg];
            h1pre[(long)m0 * 32 + 16 + l16] = acc01[reg];
        }
        if (m1 < N_NODES) {
            h1pre[(long)m1 * 32 + l16]      = acc10[reg];
            h1pre[(long)m1 * 32 + 16 + l16] = acc11[reg];
        }
    }
}

// ---------------- agg1 (pull, no atomics): h1 = relu(dq*sum(disq[s]*h1pre[s]) + dq^2*h1pre[n] + b1)
__global__ __launch_bounds__(256) void k_agg1(const int* __restrict__ rowptr,
                                              const int* __restrict__ csr,
                                              const float* __restrict__ disq,
                                              const float* __restrict__ h1pre,
                                              const float* __restrict__ b1,
                                              float* __restrict__ h1) {
    int t = blockIdx.x * 256 + threadIdx.x;
    int n = t >> 3, q = t & 7;               // 8 threads/node, float4 each (32 feats)
    if (n >= N_NODES) return;
    int e0 = rowptr[n], e1 = rowptr[n + 1];
    float4 acc = {0.f, 0.f, 0.f, 0.f};
    for (int e = e0; e < e1; e++) {
        int s = csr[e];
        float w = disq[s];
        float4 v = ((const float4*)(h1pre + (long)s * 32))[q];
        acc.x += w * v.x; acc.y += w * v.y; acc.z += w * v.z; acc.w += w * v.w;
    }
    float dq = disq[n];
    float4 self = ((const float4*)(h1pre + (long)n * 32))[q];
    float4 bb = ((const float4*)b1)[q];
    float4 r;
    r.x = fmaxf(dq * acc.x + dq * dq * self.x + bb.x, 0.f);
    r.y = fmaxf(dq * acc.y + dq * dq * self.y + bb.y, 0.f);
    r.z = fmaxf(dq * acc.z + dq * dq * self.z + bb.z, 0.f);
    r.w = fmaxf(dq * acc.w + dq * dq * self.w + bb.w, 0.f);
    ((float4*)(h1 + (long)n * 32))[q] = r;
}

// ---------------- GEMM2: h2pre = h1 @ W2 ----------------
__global__ void k_gemm2(const float* __restrict__ h1, const float* __restrict__ W2,
                        float* __restrict__ h2pre) {
    int t = blockIdx.x * 256 + threadIdx.x;
    if (t >= N_NODES * 16) return;
    int n = t >> 4, f = t & 15;
    const float4* hv = (const float4*)(h1 + (long)n * 32);
    float acc = 0.f;
#pragma unroll
    for (int kq = 0; kq < 8; kq++) {
        float4 h = hv[kq];
        acc += h.x * W2[(kq * 4 + 0) * 16 + f] + h.y * W2[(kq * 4 + 1) * 16 + f]
             + h.z * W2[(kq * 4 + 2) * 16 + f] + h.w * W2[(kq * 4 + 3) * 16 + f];
    }
    h2pre[t] = acc;
}

// ---------------- agg2 (pull, no atomics, 16 feats) ----------------
__global__ __launch_bounds__(256) void k_agg2(const int* __restrict__ rowptr,
                                              const int* __restrict__ csr,
                                              const float* __restrict__ disq,
                                              const float* __restrict__ h2pre,
                                              const float* __restrict__ b2,
                                              float* __restrict__ h2) {
    int t = blockIdx.x * 256 + threadIdx.x;
    int n = t >> 2, q = t & 3;               // 4 threads/node, float4 each (16 feats)
    if (n >= N_NODES) return;
    int e0 = rowptr[n], e1 = rowptr[n + 1];
    float4 acc = {0.f, 0.f, 0.f, 0.f};
    for (int e = e0; e < e1; e++) {
        int s = csr[e];
        float w = disq[s];
        float4 v = ((const float4*)(h2pre + (long)s * 16))[q];
        acc.x += w * v.x; acc.y += w * v.y; acc.z += w * v.z; acc.w += w * v.w;
    }
    float dq = disq[n];
    float4 self = ((const float4*)(h2pre + (long)n * 16))[q];
    float4 bb = ((const float4*)b2)[q];
    float4 r;
    r.x = fmaxf(dq * acc.x + dq * dq * self.x + bb.x, 0.f);
    r.y = fmaxf(dq * acc.y + dq * dq * self.y + bb.y, 0.f);
    r.z = fmaxf(dq * acc.z + dq * dq * self.z + bb.z, 0.f);
    r.w = fmaxf(dq * acc.w + dq * dq * self.w + bb.w, 0.f);
    ((float4*)(h2 + (long)n * 16))[q] = r;
}

// ---------------- stats: lse_acc[n] += sum_j exp(logit[n][j]) over j-chunk ----------------
// lane = node (4 nodes per lane), wave = 256 nodes; max-free logsumexp (|logit| <~ 2)
__global__ __launch_bounds__(256) void k_stats(const float* __restrict__ h2,
                                               const float* __restrict__ wlt,
                                               const float* __restrict__ bl,
                                               float* __restrict__ lseacc) {
    int wv = threadIdx.x >> 6, lane = threadIdx.x & 63;
    int jc = blockIdx.x;                 // 0..7
    int nw = blockIdx.y * 4 + wv;        // node-wave id
    int j0 = jc * 180, j1 = min(j0 + 180, F_IN);
    int nb = nw * 256 + lane;
    float hr[4][16];
    float acc[4] = {0.f, 0.f, 0.f, 0.f};
#pragma unroll
    for (int i = 0; i < 4; i++) {
        long n = min(nb + 64 * i, N_NODES - 1);
        const float4* hv = (const float4*)(h2 + n * 16);
#pragma unroll
        for (int q = 0; q < 4; q++) {
            float4 h = hv[q];
            hr[i][q * 4 + 0] = h.x; hr[i][q * 4 + 1] = h.y;
            hr[i][q * 4 + 2] = h.z; hr[i][q * 4 + 3] = h.w;
        }
    }
    for (int j = j0; j < j1; j++) {
        const float4* wv4 = (const float4*)(wlt + j * 16);
        float wk[16];
#pragma unroll
        for (int q = 0; q < 4; q++) {
            float4 w = wv4[q];
            wk[q * 4 + 0] = w.x; wk[q * 4 + 1] = w.y; wk[q * 4 + 2] = w.z; wk[q * 4 + 3] = w.w;
        }
        float b = bl[j];
#pragma unroll
        for (int i = 0; i < 4; i++) {
            float lg = b;
#pragma unroll
            for (int k = 0; k < 16; k++) lg += hr[i][k] * wk[k];
            acc[i] += __expf(lg);
        }
    }
#pragma unroll
    for (int i = 0; i < 4; i++) {
        int n = nb + 64 * i;
        if (n < N_NODES) unsafeAtomicAdd(&lseacc[n], acc[i]);
    }
}

__global__ void k_lse(float* __restrict__ lse) {
    int t = blockIdx.x * 256 + threadIdx.x;
    if (t < N_NODES) lse[t] = __logf(lse[t]);
}

// ---------------- passB: out[n][j] = logit - lse[n]  (column-stationary, coalesced stores) ----
__global__ __launch_bounds__(256) void k_passb(const float* __restrict__ h2,
                                               const float* __restrict__ Wl,
                                               const float* __restrict__ bl,
                                               const float* __restrict__ lse,
                                               float* __restrict__ out) {
    int wv = threadIdx.x >> 6, lane = threadIdx.x & 63;
    int tile = blockIdx.x;               // 0..5, 256 cols each
    float wf[4][16], bias[4];
    int cols[4]; bool cv[4];
#pragma unroll
    for (int c = 0; c < 4; c++) {
        int col = tile * 256 + c * 64 + lane;
        cv[c] = col < F_IN;
        int cc = min(col, F_IN - 1);
        cols[c] = cc;
        bias[c] = bl[cc];
#pragma unroll
        for (int k = 0; k < 16; k++) wf[c][k] = Wl[k * F_IN + cc];
    }
    int n0 = (blockIdx.y * 4 + wv) * 128;
    for (int i = 0; i < 128; i++) {
        int n = n0 + i;
        if (n >= N_NODES) break;
        const float4* hv = (const float4*)(h2 + (long)n * 16);
        float4 h0 = hv[0], h1v = hv[1], h2v = hv[2], h3v = hv[3];
        float l = lse[n];
        float* op = out + (long)n * F_IN;
#pragma unroll
        for (int c = 0; c < 4; c++) {
            float lg = bias[c]
                + h0.x * wf[c][0]  + h0.y * wf[c][1]  + h0.z * wf[c][2]  + h0.w * wf[c][3]
                + h1v.x * wf[c][4] + h1v.y * wf[c][5] + h1v.z * wf[c][6] + h1v.w * wf[c][7]
                + h2v.x * wf[c][8] + h2v.y * wf[c][9] + h2v.z * wf[c][10]+ h2v.w * wf[c][11]
                + h3v.x * wf[c][12]+ h3v.y * wf[c][13]+ h3v.z * wf[c][14]+ h3v.w * wf[c][15];
            if (cv[c]) op[cols[c]] = lg - l;
        }
    }
}

extern "C" void kernel_launch(void* const* d_in, const int* in_sizes, int n_in,
                              void* d_out, int out_size, void* d_ws, size_t ws_size,
                              hipStream_t stream) {
    const float* x  = (const float*)d_in[0];
    const float* W1 = (const float*)d_in[1];
    const float* b1 = (const float*)d_in[2];
    const float* W2 = (const float*)d_in[3];
    const float* b2 = (const float*)d_in[4];
    const float* Wl = (const float*)d_in[5];
    const float* bl = (const float*)d_in[6];
    const int*   ei = (const int*)d_in[7];
    const int E = in_sizes[7] / 2;
    const int* srcp = ei;
    const int* dstp = ei + E;

    float* ws    = (float*)d_ws;
    float* h1    = ws + O_H1ACC;   // written fully by k_agg1
    float* h2    = ws + O_H2ACC;   // written fully by k_agg2
    int*   cnt   = (int*)(ws + O_CNT);
    float* lse   = ws + O_LSE;
    float* h1pre = ws + O_H1PRE;
    float* h2pre = ws + O_H2PRE;
    float* disq  = ws + O_DISQ;
    float* wlt   = ws + O_WLT;
    __bf16* w1f  = (__bf16*)(ws + O_W1F);
    float* out   = (float*)d_out;

    // CSR scratch lives in d_out (573 MB; fully overwritten by k_passb at the end)
    int* csr    = (int*)d_out;            // E
    int* rowptr = csr + E;                // N+1
    int* fill   = rowptr + N_NODES + 1;   // N
    int* bsum   = fill + N_NODES;         // NBLK_SCAN
    int* bbase  = bsum + 128;             // 128

    // zero only cnt + lse (h1/h2 are fully written, CSR arrays fully written)
    hipMemsetAsync(ws + O_CNT, 0, 200000 * sizeof(float), stream);

    k_deg<<<(E + 255) / 256, 256, 0, stream>>>(dstp, E, cnt);
    k_disq<<<(N_NODES + 255) / 256, 256, 0, stream>>>(cnt, disq);
    k_w1f<<<(45 * 1024 + 255) / 256, 256, 0, stream>>>(W1, w1f);
    k_wlt<<<(F_IN * H2F + 255) / 256, 256, 0, stream>>>(Wl, wlt);

    // CSR build (no float atomics anywhere downstream)
    k_scansum<<<NBLK_SCAN, 256, 0, stream>>>(cnt, bsum);
    k_scanbase<<<1, 128, 0, stream>>>(bsum, bbase, rowptr);
    k_scanwrite<<<NBLK_SCAN, 256, 0, stream>>>(cnt, bbase, rowptr, fill);
    k_fill<<<(E + 255) / 256, 256, 0, stream>>>(srcp, dstp, E, fill, csr);

    k_gemm1<<<(N_NODES + 127) / 128, 256, 0, stream>>>(x, w1f, h1pre);
    k_agg1<<<(N_NODES * 8 + 255) / 256, 256, 0, stream>>>(rowptr, csr, disq, h1pre, b1, h1);

    k_gemm2<<<(N_NODES * 16 + 255) / 256, 256, 0, stream>>>(h1, W2, h2pre);
    k_agg2<<<(N_NODES * 4 + 255) / 256, 256, 0, stream>>>(rowptr, csr, disq, h2pre, b2, h2);

    k_stats<<<dim3(8, 98), 256, 0, stream>>>(h2, wlt, bl, lse);
    k_lse<<<(N_NODES + 255) / 256, 256, 0, stream>>>(lse);
    k_passb<<<dim3(6, 196), 256, 0, stream>>>(h2, Wl, bl, lse, out);
}

// Round 2
// 1969.336 us; speedup vs baseline: 1.0420x; 1.0420x over previous
//
#include <hip/hip_runtime.h>
#include <hip/hip_bf16.h>

#define N_NODES 100000
#define F_IN 1433
#define F_PAD 1440          // x padded to 1440 bf16 per row (16B-aligned rows)
#define H1F 32
#define H2F 16
#define NBLK_SCAN 98        // ceil(100000/1024)

typedef __bf16 bf16x8 __attribute__((ext_vector_type(8)));
typedef float f32x4 __attribute__((ext_vector_type(4)));

// ---- workspace layout (float offsets) ----
#define O_H1ACC 0          // 3,200,000 f  (N*32) -> h1 (written fully by k_agg1)
#define O_H2ACC 3200000    // 1,600,000 f  (N*16) -> h2 (written fully by k_agg2)
#define O_CNT   4800000    // 100,000 int  (degree counts)       [zeroed]
#define O_LSE   4900000    // 100,000 f    (sum-exp accum)       [zeroed]
#define O_H1PRE 5000000    // 3,200,000 f  (x@W1)
#define O_H2PRE 8200000    // 1,600,000 f  (h1@W2)
#define O_DISQ  9800000    // 100,000 f    (deg^-1/2)
#define O_WLT   9900000    // 24,000 f     (Wl transposed [1433][16])
#define O_W1F   9924000    // 23,040 f     (W1 packed bf16 B-fragments)

// d_out scratch (ints): [csr E][rowptr N+1][fill N][bsum][bbase] then xbf at 4M ints
#define XBF_OFF_INT 4000000

// ---------------- degree / normalization ----------------
__global__ void k_deg(const int* __restrict__ dst, int E, int* __restrict__ cnt) {
    int t = blockIdx.x * 256 + threadIdx.x;
    if (t < E) atomicAdd(&cnt[dst[t]], 1);
}

__global__ void k_disq(const int* __restrict__ cnt, float* __restrict__ disq) {
    int t = blockIdx.x * 256 + threadIdx.x;
    if (t < N_NODES) disq[t] = rsqrtf((float)(cnt[t] + 1));  // +1 self-loop
}

// ---------------- CSR build: 3-kernel coalesced exclusive scan + fill ----------------
__global__ __launch_bounds__(256) void k_scansum(const int* __restrict__ cnt,
                                                 int* __restrict__ bsum) {
    __shared__ int lds[256];
    int t = threadIdx.x, b = blockIdx.x;
    int i = b * 1024 + t * 4;
    int c0 = 0, c1 = 0, c2 = 0, c3 = 0;
    if (i + 3 < N_NODES) {
        int4 v = *(const int4*)(cnt + i);
        c0 = v.x; c1 = v.y; c2 = v.z; c3 = v.w;
    } else {
        if (i + 0 < N_NODES) c0 = cnt[i + 0];
        if (i + 1 < N_NODES) c1 = cnt[i + 1];
        if (i + 2 < N_NODES) c2 = cnt[i + 2];
        if (i + 3 < N_NODES) c3 = cnt[i + 3];
    }
    lds[t] = c0 + c1 + c2 + c3;
    __syncthreads();
    for (int off = 128; off > 0; off >>= 1) {
        if (t < off) lds[t] += lds[t + off];
        __syncthreads();
    }
    if (t == 0) bsum[b] = lds[0];
}

__global__ __launch_bounds__(128) void k_scanbase(const int* __restrict__ bsum,
                                                  int* __restrict__ bbase,
                                                  int* __restrict__ rowptr) {
    __shared__ int lds[128];
    int t = threadIdx.x;
    lds[t] = (t < NBLK_SCAN) ? bsum[t] : 0;
    __syncthreads();
    for (int off = 1; off < 128; off <<= 1) {
        int u = (t >= off) ? lds[t - off] : 0;
        __syncthreads();
        lds[t] += u;
        __syncthreads();
    }
    bbase[t] = (t == 0) ? 0 : lds[t - 1];
    if (t == NBLK_SCAN - 1) rowptr[N_NODES] = lds[t];  // total in-degree = E
}

__global__ __launch_bounds__(256) void k_scanwrite(const int* __restrict__ cnt,
                                                   const int* __restrict__ bbase,
                                                   int* __restrict__ rowptr,
                                                   int* __restrict__ fill) {
    __shared__ int lds[256];
    int t = threadIdx.x, b = blockIdx.x;
    int i = b * 1024 + t * 4;
    int c0 = 0, c1 = 0, c2 = 0, c3 = 0;
    if (i + 3 < N_NODES) {
        int4 v = *(const int4*)(cnt + i);
        c0 = v.x; c1 = v.y; c2 = v.z; c3 = v.w;
    } else {
        if (i + 0 < N_NODES) c0 = cnt[i + 0];
        if (i + 1 < N_NODES) c1 = cnt[i + 1];
        if (i + 2 < N_NODES) c2 = cnt[i + 2];
        if (i + 3 < N_NODES) c3 = cnt[i + 3];
    }
    int s = c0 + c1 + c2 + c3;
    lds[t] = s;
    __syncthreads();
    for (int off = 1; off < 256; off <<= 1) {
        int u = (t >= off) ? lds[t - off] : 0;
        __syncthreads();
        lds[t] += u;
        __syncthreads();
    }
    int p = bbase[b] + lds[t] - s;
    if (i + 0 < N_NODES) { rowptr[i + 0] = p; fill[i + 0] = p; p += c0; }
    if (i + 1 < N_NODES) { rowptr[i + 1] = p; fill[i + 1] = p; p += c1; }
    if (i + 2 < N_NODES) { rowptr[i + 2] = p; fill[i + 2] = p; p += c2; }
    if (i + 3 < N_NODES) { rowptr[i + 3] = p; fill[i + 3] = p; p += c3; }
}

__global__ void k_fill(const int* __restrict__ src, const int* __restrict__ dst, int E,
                       int* __restrict__ fill, int* __restrict__ csr) {
    int t = blockIdx.x * 256 + threadIdx.x;
    if (t < E) {
        int slot = atomicAdd(&fill[dst[t]], 1);
        csr[slot] = src[t];
    }
}

// ---------------- x -> bf16, rows padded to F_PAD (streaming, coalesced) ----------------
__global__ __launch_bounds__(256) void k_xbf(const float* __restrict__ x,
                                             __bf16* __restrict__ xbf) {
    int row = blockIdx.x;
    const float* xr = x + (long)row * F_IN;
    __bf16* o = xbf + (long)row * F_PAD;
    for (int j = threadIdx.x; j < F_PAD; j += 256) {
        float v = (j < F_IN) ? xr[j] : 0.f;
        o[j] = (__bf16)v;
    }
}

// ---------------- W1 -> bf16 B-fragment pack ----------------
// layout: [ks 0..44][ntile 0..1][lane 0..63][j 0..7]; B[k][n]: n=lane&15, k=ks*32+(lane>>4)*8+j
__global__ void k_w1f(const float* __restrict__ W1, __bf16* __restrict__ w1f) {
    int t = blockIdx.x * 256 + threadIdx.x;
    if (t >= 45 * 1024) return;
    int j = t & 7, lane = (t >> 3) & 63, nt = (t >> 9) & 1, ks = t >> 10;
    int k = ks * 32 + (lane >> 4) * 8 + j;
    int f = nt * 16 + (lane & 15);
    float v = (k < F_IN) ? W1[k * H1F + f] : 0.f;  // zero-pad K tail
    w1f[t] = (__bf16)v;
}

// ---------------- Wl transpose: wlt[j*16+k] = Wl[k*F_IN+j] ----------------
__global__ void k_wlt(const float* __restrict__ Wl, float* __restrict__ wlt) {
    int t = blockIdx.x * 256 + threadIdx.x;
    if (t < F_IN * H2F) {
        int j = t >> 4, k = t & 15;
        wlt[t] = Wl[k * F_IN + j];
    }
}

// ---------------- GEMM1: h1pre = x @ W1  (bf16 MFMA, aligned vector loads) ----------------
// wave owns 16 rows (1 m-tile); block = 4 waves = 64 rows; grid 1563
__global__ __launch_bounds__(256) void k_gemm1(const __bf16* __restrict__ xbf,
                                               const __bf16* __restrict__ w1f,
                                               float* __restrict__ h1pre) {
    const int lane = threadIdx.x & 63;
    const int wv   = threadIdx.x >> 6;
    const int l16  = lane & 15, quad = lane >> 4;
    const int rowb = blockIdx.x * 64 + wv * 16;
    const long r = min(rowb + l16, N_NODES - 1);
    const __bf16* xr = xbf + r * F_PAD + quad * 8;
    f32x4 acc0 = {0,0,0,0}, acc1 = {0,0,0,0};
    const bf16x8* bfp = (const bf16x8*)w1f;

#pragma unroll 5
    for (int ks = 0; ks < 45; ks++) {
        bf16x8 a  = *(const bf16x8*)(xr + ks * 32);
        bf16x8 b0 = bfp[(ks * 2 + 0) * 64 + lane];
        bf16x8 b1 = bfp[(ks * 2 + 1) * 64 + lane];
        acc0 = __builtin_amdgcn_mfma_f32_16x16x32_bf16(a, b0, acc0, 0, 0, 0);
        acc1 = __builtin_amdgcn_mfma_f32_16x16x32_bf16(a, b1, acc1, 0, 0, 0);
    }
    // C/D: col = lane&15 (=f), row = quad*4 + reg (node offset in tile)
#pragma unroll
    for (int reg = 0; reg < 4; reg++) {
        int m = rowb + quad * 4 + reg;
        if (m < N_NODES) {
            h1pre[(long)m * 32 + l16]      = acc0[reg];
            h1pre[(long)m * 32 + 16 + l16] = acc1[reg];
        }
    }
}

// ---------------- agg1 (pull, no atomics): h1 = relu(dq*sum(disq[s]*h1pre[s]) + dq^2*self + b1)
__global__ __launch_bounds__(256) void k_agg1(const int* __restrict__ rowptr,
                                              const int* __restrict__ csr,
                                              const float* __restrict__ disq,
                                              const float* __restrict__ h1pre,
                                              const float* __restrict__ b1,
                                              float* __restrict__ h1) {
    int t = blockIdx.x * 256 + threadIdx.x;
    int n = t >> 3, q = t & 7;               // 8 threads/node, float4 each (32 feats)
    if (n >= N_NODES) return;
    int e0 = rowptr[n], e1 = rowptr[n + 1];
    float4 acc = {0.f, 0.f, 0.f, 0.f};
    int e = e0;
    for (; e + 1 < e1; e += 2) {             // 2-way unroll: 2 gathers in flight
        int s0 = csr[e], s1 = csr[e + 1];
        float w0 = disq[s0], w1 = disq[s1];
        float4 v0 = ((const float4*)(h1pre + (long)s0 * 32))[q];
        float4 v1 = ((const float4*)(h1pre + (long)s1 * 32))[q];
        acc.x += w0 * v0.x + w1 * v1.x;
        acc.y += w0 * v0.y + w1 * v1.y;
        acc.z += w0 * v0.z + w1 * v1.z;
        acc.w += w0 * v0.w + w1 * v1.w;
    }
    if (e < e1) {
        int s = csr[e];
        float w = disq[s];
        float4 v = ((const float4*)(h1pre + (long)s * 32))[q];
        acc.x += w * v.x; acc.y += w * v.y; acc.z += w * v.z; acc.w += w * v.w;
    }
    float dq = disq[n];
    float4 self = ((const float4*)(h1pre + (long)n * 32))[q];
    float4 bb = ((const float4*)b1)[q];
    float4 r;
    r.x = fmaxf(dq * acc.x + dq * dq * self.x + bb.x, 0.f);
    r.y = fmaxf(dq * acc.y + dq * dq * self.y + bb.y, 0.f);
    r.z = fmaxf(dq * acc.z + dq * dq * self.z + bb.z, 0.f);
    r.w = fmaxf(dq * acc.w + dq * dq * self.w + bb.w, 0.f);
    ((float4*)(h1 + (long)n * 32))[q] = r;
}

// ---------------- GEMM2: h2pre = h1 @ W2 ----------------
__global__ void k_gemm2(const float* __restrict__ h1, const float* __restrict__ W2,
                        float* __restrict__ h2pre) {
    int t = blockIdx.x * 256 + threadIdx.x;
    if (t >= N_NODES * 16) return;
    int n = t >> 4, f = t & 15;
    const float4* hv = (const float4*)(h1 + (long)n * 32);
    float acc = 0.f;
#pragma unroll
    for (int kq = 0; kq < 8; kq++) {
        float4 h = hv[kq];
        acc += h.x * W2[(kq * 4 + 0) * 16 + f] + h.y * W2[(kq * 4 + 1) * 16 + f]
             + h.z * W2[(kq * 4 + 2) * 16 + f] + h.w * W2[(kq * 4 + 3) * 16 + f];
    }
    h2pre[t] = acc;
}

// ---------------- agg2 (pull, no atomics, 16 feats) ----------------
__global__ __launch_bounds__(256) void k_agg2(const int* __restrict__ rowptr,
                                              const int* __restrict__ csr,
                                              const float* __restrict__ disq,
                                              const float* __restrict__ h2pre,
                                              const float* __restrict__ b2,
                                              float* __restrict__ h2) {
    int t = blockIdx.x * 256 + threadIdx.x;
    int n = t >> 2, q = t & 3;               // 4 threads/node, float4 each (16 feats)
    if (n >= N_NODES) return;
    int e0 = rowptr[n], e1 = rowptr[n + 1];
    float4 acc = {0.f, 0.f, 0.f, 0.f};
    int e = e0;
    for (; e + 1 < e1; e += 2) {
        int s0 = csr[e], s1 = csr[e + 1];
        float w0 = disq[s0], w1 = disq[s1];
        float4 v0 = ((const float4*)(h2pre + (long)s0 * 16))[q];
        float4 v1 = ((const float4*)(h2pre + (long)s1 * 16))[q];
        acc.x += w0 * v0.x + w1 * v1.x;
        acc.y += w0 * v0.y + w1 * v1.y;
        acc.z += w0 * v0.z + w1 * v1.z;
        acc.w += w0 * v0.w + w1 * v1.w;
    }
    if (e < e1) {
        int s = csr[e];
        float w = disq[s];
        float4 v = ((const float4*)(h2pre + (long)s * 16))[q];
        acc.x += w * v.x; acc.y += w * v.y; acc.z += w * v.z; acc.w += w * v.w;
    }
    float dq = disq[n];
    float4 self = ((const float4*)(h2pre + (long)n * 16))[q];
    float4 bb = ((const float4*)b2)[q];
    float4 r;
    r.x = fmaxf(dq * acc.x + dq * dq * self.x + bb.x, 0.f);
    r.y = fmaxf(dq * acc.y + dq * dq * self.y + bb.y, 0.f);
    r.z = fmaxf(dq * acc.z + dq * dq * self.z + bb.z, 0.f);
    r.w = fmaxf(dq * acc.w + dq * dq * self.w + bb.w, 0.f);
    ((float4*)(h2 + (long)n * 16))[q] = r;
}

// ---------------- stats: lse_acc[n] += sum_j exp(logit[n][j]) over j-chunk ----------------
__global__ __launch_bounds__(256) void k_stats(const float* __restrict__ h2,
                                               const float* __restrict__ wlt,
                                               const float* __restrict__ bl,
                                               float* __restrict__ lseacc) {
    int wv = threadIdx.x >> 6, lane = threadIdx.x & 63;
    int jc = blockIdx.x;                 // 0..7
    int nw = blockIdx.y * 4 + wv;        // node-wave id
    int j0 = jc * 180, j1 = min(j0 + 180, F_IN);
    int nb = nw * 256 + lane;
    float hr[4][16];
    float acc[4] = {0.f, 0.f, 0.f, 0.f};
#pragma unroll
    for (int i = 0; i < 4; i++) {
        long n = min(nb + 64 * i, N_NODES - 1);
        const float4* hv = (const float4*)(h2 + n * 16);
#pragma unroll
        for (int q = 0; q < 4; q++) {
            float4 h = hv[q];
            hr[i][q * 4 + 0] = h.x; hr[i][q * 4 + 1] = h.y;
            hr[i][q * 4 + 2] = h.z; hr[i][q * 4 + 3] = h.w;
        }
    }
    for (int j = j0; j < j1; j++) {
        const float4* wv4 = (const float4*)(wlt + j * 16);
        float wk[16];
#pragma unroll
        for (int q = 0; q < 4; q++) {
            float4 w = wv4[q];
            wk[q * 4 + 0] = w.x; wk[q * 4 + 1] = w.y; wk[q * 4 + 2] = w.z; wk[q * 4 + 3] = w.w;
        }
        float b = bl[j];
#pragma unroll
        for (int i = 0; i < 4; i++) {
            float lg = b;
#pragma unroll
            for (int k = 0; k < 16; k++) lg += hr[i][k] * wk[k];
            acc[i] += __expf(lg);
        }
    }
#pragma unroll
    for (int i = 0; i < 4; i++) {
        int n = nb + 64 * i;
        if (n < N_NODES) unsafeAtomicAdd(&lseacc[n], acc[i]);
    }
}

__global__ void k_lse(float* __restrict__ lse) {
    int t = blockIdx.x * 256 + threadIdx.x;
    if (t < N_NODES) lse[t] = __logf(lse[t]);
}

// ---------------- passB: out[n][j] = logit - lse[n] ----------------
__global__ __launch_bounds__(256) void k_passb(const float* __restrict__ h2,
                                               const float* __restrict__ Wl,
                                               const float* __restrict__ bl,
                                               const float* __restrict__ lse,
                                               float* __restrict__ out) {
    int wv = threadIdx.x >> 6, lane = threadIdx.x & 63;
    int tile = blockIdx.x;               // 0..5, 256 cols each
    float wf[4][16], bias[4];
    int cols[4]; bool cv[4];
#pragma unroll
    for (int c = 0; c < 4; c++) {
        int col = tile * 256 + c * 64 + lane;
        cv[c] = col < F_IN;
        int cc = min(col, F_IN - 1);
        cols[c] = cc;
        bias[c] = bl[cc];
#pragma unroll
        for (int k = 0; k < 16; k++) wf[c][k] = Wl[k * F_IN + cc];
    }
    int n0 = (blockIdx.y * 4 + wv) * 128;
    for (int i = 0; i < 128; i++) {
        int n = n0 + i;
        if (n >= N_NODES) break;
        const float4* hv = (const float4*)(h2 + (long)n * 16);
        float4 h0 = hv[0], h1v = hv[1], h2v = hv[2], h3v = hv[3];
        float l = lse[n];
        float* op = out + (long)n * F_IN;
#pragma unroll
        for (int c = 0; c < 4; c++) {
            float lg = bias[c]
                + h0.x * wf[c][0]  + h0.y * wf[c][1]  + h0.z * wf[c][2]  + h0.w * wf[c][3]
                + h1v.x * wf[c][4] + h1v.y * wf[c][5] + h1v.z * wf[c][6] + h1v.w * wf[c][7]
                + h2v.x * wf[c][8] + h2v.y * wf[c][9] + h2v.z * wf[c][10]+ h2v.w * wf[c][11]
                + h3v.x * wf[c][12]+ h3v.y * wf[c][13]+ h3v.z * wf[c][14]+ h3v.w * wf[c][15];
            if (cv[c]) op[cols[c]] = lg - l;
        }
    }
}

extern "C" void kernel_launch(void* const* d_in, const int* in_sizes, int n_in,
                              void* d_out, int out_size, void* d_ws, size_t ws_size,
                              hipStream_t stream) {
    const float* x  = (const float*)d_in[0];
    const float* W1 = (const float*)d_in[1];
    const float* b1 = (const float*)d_in[2];
    const float* W2 = (const float*)d_in[3];
    const float* b2 = (const float*)d_in[4];
    const float* Wl = (const float*)d_in[5];
    const float* bl = (const float*)d_in[6];
    const int*   ei = (const int*)d_in[7];
    const int E = in_sizes[7] / 2;
    const int* srcp = ei;
    const int* dstp = ei + E;

    float* ws    = (float*)d_ws;
    float* h1    = ws + O_H1ACC;
    float* h2    = ws + O_H2ACC;
    int*   cnt   = (int*)(ws + O_CNT);
    float* lse   = ws + O_LSE;
    float* h1pre = ws + O_H1PRE;
    float* h2pre = ws + O_H2PRE;
    float* disq  = ws + O_DISQ;
    float* wlt   = ws + O_WLT;
    __bf16* w1f  = (__bf16*)(ws + O_W1F);
    float* out   = (float*)d_out;

    // d_out scratch (all consumed before k_passb overwrites d_out)
    int* csr    = (int*)d_out;                 // E
    int* rowptr = csr + E;                     // N+1
    int* fill   = rowptr + N_NODES + 1;        // N
    int* bsum   = fill + N_NODES;              // NBLK_SCAN
    int* bbase  = bsum + 128;                  // 128
    __bf16* xbf = (__bf16*)((int*)d_out + XBF_OFF_INT);  // N * F_PAD bf16 = 288 MB

    // zero only cnt + lse
    hipMemsetAsync(ws + O_CNT, 0, 200000 * sizeof(float), stream);

    k_deg<<<(E + 255) / 256, 256, 0, stream>>>(dstp, E, cnt);
    k_disq<<<(N_NODES + 255) / 256, 256, 0, stream>>>(cnt, disq);
    k_w1f<<<(45 * 1024 + 255) / 256, 256, 0, stream>>>(W1, w1f);
    k_wlt<<<(F_IN * H2F + 255) / 256, 256, 0, stream>>>(Wl, wlt);

    // CSR build
    k_scansum<<<NBLK_SCAN, 256, 0, stream>>>(cnt, bsum);
    k_scanbase<<<1, 128, 0, stream>>>(bsum, bbase, rowptr);
    k_scanwrite<<<NBLK_SCAN, 256, 0, stream>>>(cnt, bbase, rowptr, fill);
    k_fill<<<(E + 255) / 256, 256, 0, stream>>>(srcp, dstp, E, fill, csr);

    // x -> bf16 padded, then MFMA GEMM1 with aligned vector loads
    k_xbf<<<N_NODES, 256, 0, stream>>>(x, xbf);
    k_gemm1<<<(N_NODES + 63) / 64, 256, 0, stream>>>(xbf, w1f, h1pre);
    k_agg1<<<(N_NODES * 8 + 255) / 256, 256, 0, stream>>>(rowptr, csr, disq, h1pre, b1, h1);

    k_gemm2<<<(N_NODES * 16 + 255) / 256, 256, 0, stream>>>(h1, W2, h2pre);
    k_agg2<<<(N_NODES * 4 + 255) / 256, 256, 0, stream>>>(rowptr, csr, disq, h2pre, b2, h2);

    k_stats<<<dim3(8, 98), 256, 0, stream>>>(h2, wlt, bl, lse);
    k_lse<<<(N_NODES + 255) / 256, 256, 0, stream>>>(lse);
    k_passb<<<dim3(6, 196), 256, 0, stream>>>(h2, Wl, bl, lse, out);
}